// Round 6
// baseline (114.167 us; speedup 1.0000x reference)
//
#include <hip/hip_runtime.h>

// TokenEmbedding_51153060495497
// x: (256, 512, 7) f32;  kernels: (74, 8, 3) f32; keff = kernels[:,:,1]
// out flat: (256*513, 512) f32
//   row r = b*513 + t;  f in [0,512):
//     f < 511 : c = f/73, k = f%73
//     f == 511: c = 0,    k = 73
//   out[r*512+f] = sum_j xp[b, t+j-4, c] * keff[k, j]  (xp zero outside [0,512))
//
// Main path: each lane owns one 4-aligned feature quad, which (for 122 of 128
// quads) lies in a SINGLE channel -> scalar window w[8] + packed weights
// kp01/kp23 (outputs packed in v2f slots; every pk_fma slot useful).
// The 6 channel-straddling quads {18,36,54,91,109,127} skip their store and
// are produced (with the whole t=512 row) by concurrent fixup blocks.

typedef float v2f __attribute__((ext_vector_type(2)));
typedef float v4f __attribute__((ext_vector_type(4)));

#define CDIM 7
#define LDIM 512
#define TROWS 513
#define WIN_ROWS 74
#define WIN_ELEMS (WIN_ROWS * CDIM)   // 518

__device__ __forceinline__ int chan_of(int f) { return (f == 511) ? 0 : (f / 73); }
__device__ __forceinline__ int kidx_of(int f) { return (f == 511) ? 73 : (f % 73); }

__global__ __launch_bounds__(256, 4) void tok_conv_kernel(
    const float* __restrict__ x,     // (256,512,7)
    const float* __restrict__ kern,  // (74,8,3)
    float* __restrict__ out)         // (131328, 512)
{
  __shared__ float lds[WIN_ELEMS];

  const int tid   = threadIdx.x;
  const int b     = blockIdx.y;
  const int chunk = blockIdx.x;
  const float* xb = x + b * (LDIM * CDIM);

  // ---------------- fixup blocks: straddle quads + full t=512 row ----------
  if (chunk == 8) {
    const int SQ[6] = {18, 36, 54, 91, 109, 127};
    // items: 513*6 straddle quads (incl t=512 dupes, benign) + 128 row-512 quads
#pragma unroll 1
    for (int item = tid; item < 3206; item += 256) {
      int t, qq;
      if (item < 3078) { t = item / 6; qq = SQ[item - 6 * (item / 6)]; }
      else             { t = 512;      qq = item - 3078; }
      const int f0 = qq * 4;
      const int cA = chan_of(f0);
      const int cB = chan_of(f0 + 3);   // may equal cA (clean quad)

      float w0[8], w1[8];
#pragma unroll
      for (int j = 0; j < 8; ++j) {
        const int p   = t + j - 4;
        const bool ok = (unsigned)p < 512u;
        const int bse = (ok ? p : 0) * CDIM;
        const float a0 = xb[bse + cA];
        const float a1 = xb[bse + cB];
        w0[j] = ok ? a0 : 0.f;
        w1[j] = ok ? a1 : 0.f;
      }

      v4f o;
#pragma unroll
      for (int i = 0; i < 4; ++i) {
        const int  fi   = f0 + i;
        const int  ci   = chan_of(fi);
        const int  ki   = kidx_of(fi);
        const bool useB = (ci != cA);
        float s = 0.f;
#pragma unroll
        for (int j = 0; j < 8; ++j) {
          const float wv = useB ? w1[j] : w0[j];
          s = fmaf(wv, kern[ki * 24 + j * 3 + 1], s);
        }
        o[i] = s;
      }
      reinterpret_cast<v4f*>(out + ((size_t)b * TROWS + t) * 512)[qq] = o;
    }
    return;
  }

  // ---------------- main blocks: 64 rows, single-channel quads ----------
  const int q    = tid & 127;   // quad index within the row
  const int rpar = tid >> 7;    // row parity (wave-uniform)
  const int f0   = q * 4;
  const int cLo  = f0 / 73;     // channel of output f0 (f0 != 511 here)
  const bool keep = (chan_of(f0) == chan_of(f0 + 3));  // false for 6 straddle quads

  // packed weights: kp01[j] = (k[out0][j], k[out1][j]); foreign-channel -> 0
  v2f kp01[8], kp23[8];
#pragma unroll
  for (int j = 0; j < 8; ++j) {
    float kv[4];
#pragma unroll
    for (int i = 0; i < 4; ++i) {
      const int fi = f0 + i;
      const int ci = chan_of(fi);
      const int ki = kidx_of(fi);
      const float v = kern[ki * 24 + j * 3 + 1];
      kv[i] = (ci == cLo) ? v : 0.f;
    }
    kp01[j] = (v2f){kv[0], kv[1]};
    kp23[j] = (v2f){kv[2], kv[3]};
  }

  const int t0 = chunk * 64;

  // stage x[t0-4 .. t0+69] x 7ch into LDS (zero-padded, coalesced)
#pragma unroll
  for (int i = tid; i < WIN_ELEMS; i += 256) {
    const int r = i / CDIM;
    const int c = i - r * CDIM;
    const int p = t0 - 4 + r;
    lds[i] = ((unsigned)p < 512u) ? xb[p * CDIM + c] : 0.f;
  }
  __syncthreads();

  // scalar window for channel cLo; tap j of step s at lds[(rpar+2s+j)*7 + cLo]
  int bx = rpar * CDIM + cLo;

  float w[8];
#pragma unroll
  for (int j = 0; j < 8; ++j) w[j] = lds[bx + j * CDIM];

  v4f* orow =
      reinterpret_cast<v4f*>(out + ((size_t)b * TROWS + t0 + rpar) * 512) + q;

#pragma unroll 1
  for (int s4 = 0; s4 < 8; ++s4) {   // 8 groups x 4 steps = 32 rows/thread
#pragma unroll
    for (int u = 0; u < 4; ++u) {
      const int base = 2 * u;        // compile-time window rotation

      // prefetch next row-pair's 2 new taps (immediate LDS offsets)
      const float n0 = lds[bx + (2 * u + 8) * CDIM];
      const float n1 = lds[bx + (2 * u + 9) * CDIM];

      v2f a01 = {0.f, 0.f}, a23 = {0.f, 0.f};
#pragma unroll
      for (int j = 0; j < 8; ++j) {
        const float ws = w[(base + j) & 7];
        const v2f wsv = {ws, ws};        // splat -> VOP3P op_sel
        a01 += wsv * kp01[j];            // v_pk_fma_f32, both slots useful
        a23 += wsv * kp23[j];
      }
      const v4f o = {a01.x, a01.y, a23.x, a23.y};
      if (keep) *orow = o;               // straddle quads handled by fixup
      orow += 2 * 128;                   // advance 2 rows

      w[base & 7]       = n0;
      w[(base + 1) & 7] = n1;
    }
    bx += 8 * CDIM;                      // 4 steps x 2 rows
  }
}

extern "C" void kernel_launch(void* const* d_in, const int* in_sizes, int n_in,
                              void* d_out, int out_size, void* d_ws, size_t ws_size,
                              hipStream_t stream) {
  const float* x    = (const float*)d_in[0];
  const float* kern = (const float*)d_in[1];
  float* out        = (float*)d_out;

  dim3 grid(9, 256);   // chunks 0..7: 64-row main; chunk 8: fixup (concurrent)
  tok_conv_kernel<<<grid, 256, 0, stream>>>(x, kern, out);
}

// Round 7
// 61.065 us; speedup vs baseline: 1.8696x; 1.8696x over previous
//
#include <hip/hip_runtime.h>

// TokenEmbedding_51153060495497
// x: (256, 512, 7) f32;  kernels: (74, 8, 3) f32; keff = kernels[:,:,1]
// out flat: (256*513, 512) f32
//   row r = b*513 + t;  f in [0,512):
//     f < 511 : c = f/73, k = f%73
//     f == 511: c = 0,    k = 73
//   out[r*512+f] = sum_j xp[b, t+j-4, c] * keff[k, j]  (xp zero outside [0,512))
//
// Pair version: each thread owns ONE feature pair (f=2p, 2p+1). Window and
// weights are v2f packed per output -> every pk_fma slot useful, straddle
// pairs (36,109,182,255) handled natively, stores fully dense.
// ~50 VGPR -> 8 waves/SIMD.

typedef float v2f __attribute__((ext_vector_type(2)));

#define CDIM 7
#define TROWS 513
#define CHUNK 32
#define WIN_ROWS 40                    // CHUNK + 8
#define WIN_ELEMS (WIN_ROWS * CDIM)    // 280

__device__ __forceinline__ int chan_of(int f) { return (f == 511) ? 0 : (f / 73); }
__device__ __forceinline__ int kidx_of(int f) { return (f == 511) ? 73 : (f % 73); }

__global__ __launch_bounds__(256, 8) void tok_conv_kernel(
    const float* __restrict__ x,     // (256,512,7)
    const float* __restrict__ kern,  // (74,8,3)
    float* __restrict__ out)         // (131328, 512)
{
  __shared__ float lds[WIN_ELEMS];

  const int tid   = threadIdx.x;     // pair index 0..255
  const int b     = blockIdx.y;
  const int chunk = blockIdx.x;      // 0..16
  const float* xb = x + b * (512 * CDIM);

  const int f0 = 2 * tid, f1 = f0 + 1;
  const int c0 = chan_of(f0), k0 = kidx_of(f0);
  const int c1 = chan_of(f1), k1 = kidx_of(f1);

  // packed weights: kp[j] = (keff[k0][j], keff[k1][j]) — no zero slots
  v2f kp[8];
#pragma unroll
  for (int j = 0; j < 8; ++j)
    kp[j] = (v2f){kern[k0 * 24 + j * 3 + 1], kern[k1 * 24 + j * 3 + 1]};

  // ---- tail chunk: the single t=512 row ----
  if (chunk == 16) {
    v2f acc = {0.f, 0.f};
#pragma unroll
    for (int j = 0; j < 8; ++j) {
      const int p   = 508 + j;          // t=512: taps p = 508..515
      const bool ok = p < 512;
      const int bse = (ok ? p : 0) * CDIM;
      v2f w;
      w.x = ok ? xb[bse + c0] : 0.f;
      w.y = ok ? xb[bse + c1] : 0.f;
      acc += w * kp[j];
    }
    reinterpret_cast<v2f*>(out + ((size_t)b * TROWS + 512) * 512)[tid] = acc;
    return;
  }

  const int t0 = chunk * CHUNK;

  // ---- stage rows t0-4 .. t0+35 (x7 ch) into LDS, zero-padded ----
#pragma unroll
  for (int i = tid; i < WIN_ELEMS; i += 256) {
    const int r = i / CDIM;
    const int c = i - r * CDIM;
    const int p = t0 - 4 + r;
    lds[i] = ((unsigned)p < 512u) ? xb[p * CDIM + c] : 0.f;
  }
  __syncthreads();

  // tap j of step s lives at lds[(s+j)*7 + c]
  int bx0 = c0, bx1 = c1;

  // initial window (step 0, taps 0..7)
  v2f w[8];
#pragma unroll
  for (int j = 0; j < 8; ++j)
    w[j] = (v2f){lds[bx0 + j * CDIM], lds[bx1 + j * CDIM]};

  v2f* orow = reinterpret_cast<v2f*>(out + ((size_t)b * TROWS + t0) * 512) + tid;

#pragma unroll 1
  for (int g = 0; g < 4; ++g) {        // 4 groups x 8 steps = 32 rows
#pragma unroll
    for (int u = 0; u < 8; ++u) {
      // prefetch next row's taps (immediate LDS offsets from bx)
      v2f nv;
      nv.x = lds[bx0 + (u + 8) * CDIM];
      nv.y = lds[bx1 + (u + 8) * CDIM];

      v2f acc = {0.f, 0.f};
#pragma unroll
      for (int j = 0; j < 8; ++j)
        acc += w[(u + j) & 7] * kp[j];   // v_pk_fma_f32, both slots useful

      *orow = acc;                        // dense 8B store, 512B/wave
      orow += 256;                        // next row (512 floats)

      w[u & 7] = nv;                      // slide window by one row
    }
    bx0 += 8 * CDIM;
    bx1 += 8 * CDIM;
  }
}

extern "C" void kernel_launch(void* const* d_in, const int* in_sizes, int n_in,
                              void* d_out, int out_size, void* d_ws, size_t ws_size,
                              hipStream_t stream) {
  const float* x    = (const float*)d_in[0];
  const float* kern = (const float*)d_in[1];
  float* out        = (float*)d_out;

  dim3 grid(17, 256);   // chunks 0..15: 32-row stream; chunk 16: t=512 row
  tok_conv_kernel<<<grid, 256, 0, stream>>>(x, kern, out);
}

// Round 8
// 55.859 us; speedup vs baseline: 2.0438x; 1.0932x over previous
//
#include <hip/hip_runtime.h>

// TokenEmbedding_51153060495497
// x: (256, 512, 7) f32;  kernels: (74, 8, 3) f32; keff = kernels[:,:,1]
// out flat: (256*513, 512) f32
//   row r = b*513 + t;  f in [0,512):
//     f < 511 : c = f/73, k = f%73
//     f == 511: c = 0,    k = 73
//   out[r*512+f] = sum_j xp[b, t+j-4, c] * keff[k, j]  (xp zero outside [0,512))
//
// Pair version, 64-row chunks: each thread owns ONE feature pair (f=2p,2p+1),
// walks 64 rows. LDS stage is a single aligned float4 per thread for interior
// chunks. Dense 8B stores, ~50 VGPR -> 8 waves/SIMD.

typedef float v2f __attribute__((ext_vector_type(2)));
typedef float v4f __attribute__((ext_vector_type(4)));

#define CDIM 7
#define TROWS 513
#define CHUNK 64
#define WIN_ROWS 72                    // CHUNK + 8
#define WIN_ELEMS (WIN_ROWS * CDIM)    // 504 floats = 126 float4

__device__ __forceinline__ int chan_of(int f) { return (f == 511) ? 0 : (f / 73); }
__device__ __forceinline__ int kidx_of(int f) { return (f == 511) ? 73 : (f % 73); }

__global__ __launch_bounds__(256, 8) void tok_conv_kernel(
    const float* __restrict__ x,     // (256,512,7)
    const float* __restrict__ kern,  // (74,8,3)
    float* __restrict__ out)         // (131328, 512)
{
  __shared__ __align__(16) float lds[WIN_ELEMS];

  const int tid   = threadIdx.x;     // pair index 0..255
  const int b     = blockIdx.y;
  const int chunk = blockIdx.x;      // 0..8
  const float* xb = x + b * (512 * CDIM);

  const int f0 = 2 * tid, f1 = f0 + 1;
  const int c0 = chan_of(f0), k0 = kidx_of(f0);
  const int c1 = chan_of(f1), k1 = kidx_of(f1);

  // packed weights: kp[j] = (keff[k0][j], keff[k1][j]) — no zero slots
  v2f kp[8];
#pragma unroll
  for (int j = 0; j < 8; ++j)
    kp[j] = (v2f){kern[k0 * 24 + j * 3 + 1], kern[k1 * 24 + j * 3 + 1]};

  // ---- tail chunk: the single t=512 row ----
  if (chunk == 8) {
    v2f acc = {0.f, 0.f};
#pragma unroll
    for (int j = 0; j < 8; ++j) {
      const int p   = 508 + j;          // t=512: taps p = 508..515
      const bool ok = p < 512;
      const int bse = (ok ? p : 0) * CDIM;
      v2f w;
      w.x = ok ? xb[bse + c0] : 0.f;
      w.y = ok ? xb[bse + c1] : 0.f;
      acc += w * kp[j];
    }
    reinterpret_cast<v2f*>(out + ((size_t)b * TROWS + 512) * 512)[tid] = acc;
    return;
  }

  const int t0 = chunk * CHUNK;

  // ---- stage rows t0-4 .. t0+67 (x7 ch) into LDS ----
  if (chunk >= 1 && chunk <= 6) {
    // interior: no padding needed; (t0-4)*7 floats offset is 16B-aligned
    const v4f* src = reinterpret_cast<const v4f*>(xb + (t0 - 4) * CDIM);
    if (tid < WIN_ELEMS / 4)
      reinterpret_cast<v4f*>(lds)[tid] = src[tid];
  } else {
    // edge chunks: scalar with zero-padding
#pragma unroll
    for (int i = tid; i < WIN_ELEMS; i += 256) {
      const int r = i / CDIM;
      const int c = i - r * CDIM;
      const int p = t0 - 4 + r;
      lds[i] = ((unsigned)p < 512u) ? xb[p * CDIM + c] : 0.f;
    }
  }
  __syncthreads();

  // tap j of step s lives at lds[(s+j)*7 + c]
  int bx0 = c0, bx1 = c1;

  // initial window (step 0, taps 0..7)
  v2f w[8];
#pragma unroll
  for (int j = 0; j < 8; ++j)
    w[j] = (v2f){lds[bx0 + j * CDIM], lds[bx1 + j * CDIM]};

  v2f* orow = reinterpret_cast<v2f*>(out + ((size_t)b * TROWS + t0) * 512) + tid;

#pragma unroll 1
  for (int g = 0; g < 8; ++g) {        // 8 groups x 8 steps = 64 rows
#pragma unroll
    for (int u = 0; u < 8; ++u) {
      // prefetch next row's taps (immediate LDS offsets from bx)
      v2f nv;
      nv.x = lds[bx0 + (u + 8) * CDIM];
      nv.y = lds[bx1 + (u + 8) * CDIM];

      v2f acc = {0.f, 0.f};
#pragma unroll
      for (int j = 0; j < 8; ++j)
        acc += w[(u + j) & 7] * kp[j];   // v_pk_fma_f32, both slots useful

      *orow = acc;                        // dense 8B store, 512B/wave
      orow += 256;                        // next row (512 floats)

      w[u & 7] = nv;                      // slide window by one row
    }
    bx0 += 8 * CDIM;
    bx1 += 8 * CDIM;
  }
}

extern "C" void kernel_launch(void* const* d_in, const int* in_sizes, int n_in,
                              void* d_out, int out_size, void* d_ws, size_t ws_size,
                              hipStream_t stream) {
  const float* x    = (const float*)d_in[0];
  const float* kern = (const float*)d_in[1];
  float* out        = (float*)d_out;

  dim3 grid(9, 256);   // chunks 0..7: 64-row stream; chunk 8: t=512 row
  tok_conv_kernel<<<grid, 256, 0, stream>>>(x, kern, out);
}